// Round 11
// baseline (347.574 us; speedup 1.0000x reference)
//
#include <hip/hip_runtime.h>

#define T_STEPS 512
#define BT 32          // batches per block: TWO independent 16-col tiles (waves 0-3 / 4-7)
#define XSTRIDE 524    // padded x row stride (floats); 2096B rows, 16B aligned
#define HSTRIDE 72     // f16 per h row: 64 + 8 pad (144B rows, 16B aligned)

typedef __attribute__((ext_vector_type(8))) _Float16 f16x8;
typedef __attribute__((ext_vector_type(4))) _Float16 f16x4;
typedef __attribute__((ext_vector_type(4))) float f32x4;

__device__ __forceinline__ float exp2_fast(float x) {
#if __has_builtin(__builtin_amdgcn_exp2f)
    return __builtin_amdgcn_exp2f(x);
#else
    return __expf(x * 0.69314718056f);
#endif
}

#define L2E 1.44269504089f   // log2(e)
#define C2  2.88539008178f   // 2*log2(e)

__global__ __launch_bounds__(512, 2) void lstm_persist(
    const float* __restrict__ x,      // [B, T] (IN=1 folded)
    const float* __restrict__ W_ih,   // [256]
    const float* __restrict__ W_hh,   // [256,64]
    const float* __restrict__ b_ih,   // [256]
    const float* __restrict__ b_hh,   // [256]
    const float* __restrict__ W_fc,   // [64]
    const float* __restrict__ b_fc,   // [1]
    float* __restrict__ out)          // [B]
{
    __shared__ __align__(16) float x_lds[BT * XSTRIDE];         // 67 KB
    __shared__ __align__(16) _Float16 hbuf[2][2][16][HSTRIDE];  // 9.2 KB [buf][tile][b][k]

    const int tid  = threadIdx.x;
    const int wave = tid >> 6;     // 0..7
    const int tile = wave >> 2;    // 0: batches 0-15, 1: batches 16-31
    const int w4   = wave & 3;     // k-slice within tile: k in [16*w4, 16*w4+16)
    const int lane = tid & 63;
    const int l15  = lane & 15;    // batch index within tile (output col)
    const int quad = lane >> 4;    // 0..3
    const int b0   = blockIdx.x * BT;

    // ---- stage x[b0..b0+31][0..511] into LDS (coalesced float4, 512 threads) ----
    {
        const float* xg = x + (size_t)b0 * T_STEPS;
        #pragma unroll
        for (int i = 0; i < 8; ++i) {
            int f4 = tid + i * 512;        // 0..4095 float4 chunks
            int b  = f4 >> 7;              // 128 float4 per row
            int t4 = f4 & 127;
            float4 v = reinterpret_cast<const float4*>(xg + (size_t)b * T_STEPS)[t4];
            reinterpret_cast<float4*>(&x_lds[b * XSTRIDE + t4 * 4])[0] = v;
        }
    }
    // ---- zero h buffer 0 (both tiles) + x pad words (pad feeds a dead iv at loop end) ----
    {
        _Float16* p = &hbuf[0][0][0][0];
        for (int i = tid; i < 2 * 16 * HSTRIDE; i += 512) p[i] = (_Float16)0.f;
        if (tid < 128) {                   // 32 rows x 4 pad words
            int rw = tid >> 2, j = tid & 3;
            x_lds[rw * XSTRIDE + 512 + j] = 0.f;
        }
    }

    // ---- per-lane resident W_hh fragments (f16, RNE, scaled) ----
    // Gate scales folded in: i,f,o rows by -log2e; g rows by -2*log2e.
    // A-frag (K=32, group m): lane holds A[m=l15][k=quad*8+j] = W'[row][m*32+quad*8+j].
    // Identical for both tiles (same W); tile only selects data rows.
    const float scg[4] = { -L2E, -L2E, -C2, -L2E };
    f16x8 Wf[4][2];                // [gate][m]
    f32x4 bias4[4], wih4[4];
    #pragma unroll
    for (int g = 0; g < 4; ++g) {
        int na = g * 64 + w4 * 16 + l15;
        #pragma unroll
        for (int m = 0; m < 2; ++m) {
            const float* wr = W_hh + na * 64 + m * 32 + quad * 8;
            f16x8 a;
            #pragma unroll
            for (int j = 0; j < 8; ++j) a[j] = (_Float16)(wr[j] * scg[g]);  // RNE cvt
            Wf[g][m] = a;
        }
        // D layout: col = l15 (batch), row = quad*4 + r ->
        // lane owns gate g, k_hidden = w4*16 + quad*4 + r, batch tile*16+l15.
        #pragma unroll
        for (int r = 0; r < 4; ++r) {
            int n = g * 64 + w4 * 16 + quad * 4 + r;
            bias4[g][r] = scg[g] * (b_ih[n] + b_hh[n]);
            wih4[g][r]  = scg[g] * W_ih[n];
        }
    }

    f32x4 ct4 = {0.f, 0.f, 0.f, 0.f};   // cell state, scaled by 2*log2e
    _Float16* hb0 = &hbuf[0][tile][0][0];
    _Float16* hb1 = &hbuf[1][tile][0][0];
    const int hoff = l15 * HSTRIDE + quad * 8;             // B-frag base (f16), +32 for m=1
    const int wofs = l15 * HSTRIDE + w4 * 16 + quad * 4;   // write base (f16), 8B-aligned
    const f32x4* xrow4 = reinterpret_cast<const f32x4*>(&x_lds[(tile * 16 + l15) * XSTRIDE]);

    const f32x4 vone  = {1.f, 1.f, 1.f, 1.f};
    const f32x4 vnC2  = {-C2, -C2, -C2, -C2};
    const f32x4 vC2   = {C2, C2, C2, C2};
    const f32x4 vn40  = {-40.f, -40.f, -40.f, -40.f};

    __syncthreads();

    f32x4 xq = xrow4[0];           // x[t=0..3] for this lane's batch
    f32x4 iv[4];
    {
        f32x4 xv4 = {xq[0], xq[0], xq[0], xq[0]};
        #pragma unroll
        for (int g = 0; g < 4; ++g)
            iv[g] = __builtin_elementwise_fma(wih4[g], xv4, bias4[g]);
    }

    #pragma unroll 2
    for (int tg = 0; tg < T_STEPS / 4; ++tg) {
        f32x4 xqn = xrow4[tg + 1];     // x[t+4..t+7]; tg=127 reads zeroed pad (dead iv)
        #pragma unroll
        for (int u = 0; u < 4; ++u) {
            const _Float16* hbR = (u & 1) ? hb1 : hb0;     // compile-time parity
            _Float16*       hbW = (u & 1) ? hb0 : hb1;

            // 2 ds_read_b128: B-fragments for K-groups m=0,1
            f16x8 bm0 = *reinterpret_cast<const f16x8*>(hbR + hoff);
            f16x8 bm1 = *reinterpret_cast<const f16x8*>(hbR + hoff + 32);

            // next-step iv prefetch: independent of ds_reads, fills read-latency window
            f32x4 ivn[4];
            {
                float xn = (u < 3) ? xq[u + 1] : xqn[0];
                f32x4 xn4 = {xn, xn, xn, xn};
                #pragma unroll
                for (int g = 0; g < 4; ++g)
                    ivn[g] = __builtin_elementwise_fma(wih4[g], xn4, bias4[g]);
            }

            // 8 MFMAs: 4 parallel gate-chains, depth 2
            f32x4 acc[4];
            #pragma unroll
            for (int g = 0; g < 4; ++g)
                acc[g] = __builtin_amdgcn_mfma_f32_16x16x32_f16(Wf[g][0], bm0, iv[g], 0, 0, 0);
            #pragma unroll
            for (int g = 0; g < 4; ++g)
                acc[g] = __builtin_amdgcn_mfma_f32_16x16x32_f16(Wf[g][1], bm1, acc[g], 0, 0, 0);
            #pragma unroll
            for (int g = 0; g < 4; ++g) iv[g] = ivn[g];

            // activations in scaled domain, vectorized f32x4 (acc IS the exp2 arg)
            f32x4 ei, ef, eg, eo;
            #pragma unroll
            for (int r = 0; r < 4; ++r) {
                ei[r] = exp2_fast(acc[0][r]);
                ef[r] = exp2_fast(acc[1][r]);
                eg[r] = exp2_fast(acc[2][r]);
                eo[r] = exp2_fast(acc[3][r]);
            }
            f32x4 Ai = vone + ei, Af = vone + ef, Ag = vone + eg, Ao = vone + eo;
            f32x4 P   = Ai * Ag;
            f32x4 PAF = P * Af;
            f32x4 rP;
            #pragma unroll
            for (int r = 0; r < 4; ++r) rP[r] = __builtin_amdgcn_rcpf(PAF[r]);
            f32x4 tg4 = __builtin_elementwise_fma(vnC2, eg, vC2);   // C2*(1-eg), signed
            f32x4 num = __builtin_elementwise_fma(ct4, P, tg4 * Af);
            f32x4 cn  = num * rP;                                   // scaled cell state
            ct4 = cn;
            // ec = exp2(-max(cn,-40)): neg folds into v_exp src modifier
            f32x4 mx = __builtin_elementwise_max(cn, vn40);
            f32x4 ec;
            #pragma unroll
            for (int r = 0; r < 4; ++r) ec[r] = exp2_fast(-mx[r]);
            f32x4 den = __builtin_elementwise_fma(Ao, ec, Ao);      // Ao*(1+ec)
            f32x4 rden;
            #pragma unroll
            for (int r = 0; r < 4; ++r) rden[r] = __builtin_amdgcn_rcpf(den[r]);
            // hv = (1-ec)*rden = fma(-ec, rden, rden): 1 pk op, shorter chain
            f32x4 hv = __builtin_elementwise_fma(-ec, rden, rden);

            // f16 pack (RNE via v_cvt_f16_f32) + ONE ds_write_b64 per lane
            f16x4 h16 = { (_Float16)hv[0], (_Float16)hv[1],
                          (_Float16)hv[2], (_Float16)hv[3] };
            *reinterpret_cast<f16x4*>(hbW + wofs) = h16;

            __syncthreads();   // h(t+1) visible (both tiles); protects buffer reuse
        }
        xq = xqn;
    }

    // ---- final FC: out[b] = sum_k h[b][k]*W_fc[k] + b_fc  (h = buf 0 after t=511) ----
    if (tid < BT) {
        int b = tid;
        float s = b_fc[0];
        #pragma unroll 4
        for (int k = 0; k < 64; ++k) {
            s += (float)hbuf[0][b >> 4][b & 15][k] * W_fc[k];
        }
        out[b0 + b] = s;
    }
}

extern "C" void kernel_launch(void* const* d_in, const int* in_sizes, int n_in,
                              void* d_out, int out_size, void* d_ws, size_t ws_size,
                              hipStream_t stream) {
    const float* x    = (const float*)d_in[0];
    const float* W_ih = (const float*)d_in[1];
    const float* W_hh = (const float*)d_in[2];
    const float* b_ih = (const float*)d_in[3];
    const float* b_hh = (const float*)d_in[4];
    const float* W_fc = (const float*)d_in[5];
    const float* b_fc = (const float*)d_in[6];
    float* out = (float*)d_out;
    const int B = in_sizes[0] / T_STEPS;   // 4096
    lstm_persist<<<dim3(B / BT), dim3(512), 0, stream>>>(
        x, W_ih, W_hh, b_ih, b_hh, W_fc, b_fc, out);
}

// Round 13
// 261.239 us; speedup vs baseline: 1.3305x; 1.3305x over previous
//
#include <hip/hip_runtime.h>

#define T_STEPS 512
#define BT 16          // batches per block (one 16-col MFMA tile, batch = l15)
#define XSTRIDE 524    // padded x row stride (floats); 2096B rows, 16B aligned
#define HSTRIDE 72     // f16 per h row: 64 + 8 pad (144B rows, 16B aligned)

typedef __attribute__((ext_vector_type(8))) _Float16 f16x8;
typedef __attribute__((ext_vector_type(4))) _Float16 f16x4;
typedef __attribute__((ext_vector_type(4))) float f32x4;

__device__ __forceinline__ float exp2_fast(float x) {
#if __has_builtin(__builtin_amdgcn_exp2f)
    return __builtin_amdgcn_exp2f(x);
#else
    return __expf(x * 0.69314718056f);
#endif
}

#define L2E 1.44269504089f   // log2(e)
#define C2  2.88539008178f   // 2*log2(e)

__global__ __launch_bounds__(256, 1) void lstm_persist(
    const float* __restrict__ x,      // [B, T] (IN=1 folded)
    const float* __restrict__ W_ih,   // [256]
    const float* __restrict__ W_hh,   // [256,64]
    const float* __restrict__ b_ih,   // [256]
    const float* __restrict__ b_hh,   // [256]
    const float* __restrict__ W_fc,   // [64]
    const float* __restrict__ b_fc,   // [1]
    float* __restrict__ out)          // [B]
{
    __shared__ __align__(16) float x_lds[BT * XSTRIDE];      // 33.5 KB
    __shared__ __align__(16) _Float16 hbuf[2][BT][HSTRIDE];  // 4.6 KB, h as plain f16

    const int tid  = threadIdx.x;
    const int wave = tid >> 6;     // 0..3  -> k-slice: k in [16w, 16w+16)
    const int lane = tid & 63;
    const int l15  = lane & 15;    // batch index (output col)
    const int quad = lane >> 4;    // 0..3
    const int b0   = blockIdx.x * BT;

    // ---- stage x[b0..b0+15][0..511] into LDS (coalesced float4) ----
    {
        const float* xg = x + (size_t)b0 * T_STEPS;
        #pragma unroll
        for (int i = 0; i < 8; ++i) {
            int f4 = tid + i * 256;        // 0..2047 float4 chunks
            int b  = f4 >> 7;              // 128 float4 per row
            int t4 = f4 & 127;
            float4 v = reinterpret_cast<const float4*>(xg + (size_t)b * T_STEPS)[t4];
            reinterpret_cast<float4*>(&x_lds[b * XSTRIDE + t4 * 4])[0] = v;
        }
    }
    // ---- zero h buffer 0 + x pad words (pad feeds a dead iv at loop end) ----
    {
        _Float16* p = &hbuf[0][0][0];
        for (int i = tid; i < BT * HSTRIDE; i += 256) p[i] = (_Float16)0.f;
        if (tid < BT) {
            x_lds[tid * XSTRIDE + 512] = 0.f;
            x_lds[tid * XSTRIDE + 513] = 0.f;
            x_lds[tid * XSTRIDE + 514] = 0.f;
            x_lds[tid * XSTRIDE + 515] = 0.f;
        }
    }

    // ---- per-lane resident W_hh fragments (f16, RNE, scaled) ----
    // Gate scales folded in: i,f,o rows by -log2e; g rows by -2*log2e.
    // A-frag (K=32, group m): lane holds A[m=l15][k=quad*8+j] = W'[row][m*32+quad*8+j].
    const float scg[4] = { -L2E, -L2E, -C2, -L2E };
    f16x8 Wf[4][2];                // [gate][m]
    f32x4 bias4[4], wih4[4];
    #pragma unroll
    for (int g = 0; g < 4; ++g) {
        int na = g * 64 + wave * 16 + l15;
        #pragma unroll
        for (int m = 0; m < 2; ++m) {
            const float* wr = W_hh + na * 64 + m * 32 + quad * 8;
            f16x8 a;
            #pragma unroll
            for (int j = 0; j < 8; ++j) a[j] = (_Float16)(wr[j] * scg[g]);  // RNE cvt
            Wf[g][m] = a;
        }
        // D layout: col = l15 (batch), row = quad*4 + r ->
        // lane owns gate g, k_hidden = wave*16 + quad*4 + r, batch l15.
        #pragma unroll
        for (int r = 0; r < 4; ++r) {
            int n = g * 64 + wave * 16 + quad * 4 + r;
            bias4[g][r] = scg[g] * (b_ih[n] + b_hh[n]);
            wih4[g][r]  = scg[g] * W_ih[n];
        }
    }

    f32x4 ct4 = {0.f, 0.f, 0.f, 0.f};   // cell state, scaled by 2*log2e
    const int hoff = l15 * HSTRIDE + quad * 8;            // B-frag base (f16), +32 for m=1
    const int wofs = l15 * HSTRIDE + wave * 16 + quad * 4; // write base (f16), 8B-aligned
    const f32x4* xrow4 = reinterpret_cast<const f32x4*>(&x_lds[l15 * XSTRIDE]);

    const f32x4 vone  = {1.f, 1.f, 1.f, 1.f};
    const f32x4 vnC2  = {-C2, -C2, -C2, -C2};
    const f32x4 vC2   = {C2, C2, C2, C2};
    const f32x4 vn40  = {-40.f, -40.f, -40.f, -40.f};

    __syncthreads();

    f32x4 xq = xrow4[0];           // x[t=0..3] for this lane's batch
    f32x4 iv[4];
    {
        f32x4 xv4 = {xq[0], xq[0], xq[0], xq[0]};
        #pragma unroll
        for (int g = 0; g < 4; ++g)
            iv[g] = __builtin_elementwise_fma(wih4[g], xv4, bias4[g]);
    }

    #pragma unroll 2
    for (int tg = 0; tg < T_STEPS / 4; ++tg) {
        f32x4 xqn = xrow4[tg + 1];     // x[t+4..t+7]; tg=127 reads zeroed pad (dead iv)
        #pragma unroll
        for (int u = 0; u < 4; ++u) {
            const int rb = u & 1, wb = rb ^ 1;     // compile-time buffer parity
            const _Float16* hb = &hbuf[rb][0][0];

            // 2 ds_read_b128: B-fragments for K-groups m=0,1
            f16x8 bm0 = *reinterpret_cast<const f16x8*>(hb + hoff);
            f16x8 bm1 = *reinterpret_cast<const f16x8*>(hb + hoff + 32);

            // 8 MFMAs: 4 parallel gate-chains, depth 2
            f32x4 acc[4];
            #pragma unroll
            for (int g = 0; g < 4; ++g)
                acc[g] = __builtin_amdgcn_mfma_f32_16x16x32_f16(Wf[g][0], bm0, iv[g], 0, 0, 0);
            #pragma unroll
            for (int g = 0; g < 4; ++g)
                acc[g] = __builtin_amdgcn_mfma_f32_16x16x32_f16(Wf[g][1], bm1, acc[g], 0, 0, 0);

            // next-step iv prefetch in the MFMA-latency shadow (x from registers)
            {
                float xn = (u < 3) ? xq[u + 1] : xqn[0];
                f32x4 xn4 = {xn, xn, xn, xn};
                #pragma unroll
                for (int g = 0; g < 4; ++g)
                    iv[g] = __builtin_elementwise_fma(wih4[g], xn4, bias4[g]);
            }

            // activations in scaled domain, vectorized f32x4 (acc IS the exp2 arg)
            f32x4 ei, ef, eg, eo;
            #pragma unroll
            for (int r = 0; r < 4; ++r) {
                ei[r] = exp2_fast(acc[0][r]);
                ef[r] = exp2_fast(acc[1][r]);
                eg[r] = exp2_fast(acc[2][r]);
                eo[r] = exp2_fast(acc[3][r]);
            }
            f32x4 Ai = vone + ei, Af = vone + ef, Ag = vone + eg, Ao = vone + eo;
            f32x4 P   = Ai * Ag;
            f32x4 PAF = P * Af;
            f32x4 rP;
            #pragma unroll
            for (int r = 0; r < 4; ++r) rP[r] = __builtin_amdgcn_rcpf(PAF[r]);
            f32x4 tg4 = __builtin_elementwise_fma(vnC2, eg, vC2);   // C2*(1-eg), signed
            f32x4 num = __builtin_elementwise_fma(ct4, P, tg4 * Af);
            f32x4 cn  = num * rP;                                   // scaled cell state
            ct4 = cn;
            // ec = exp2(min(-cn,40)) == exp2(-max(cn,-40)): neg folds into v_exp src mod
            f32x4 mx = __builtin_elementwise_max(cn, vn40);
            f32x4 ec;
            #pragma unroll
            for (int r = 0; r < 4; ++r) ec[r] = exp2_fast(-mx[r]);
            f32x4 den = __builtin_elementwise_fma(Ao, ec, Ao);      // Ao*(1+ec), 1 pk op
            f32x4 rden;
            #pragma unroll
            for (int r = 0; r < 4; ++r) rden[r] = __builtin_amdgcn_rcpf(den[r]);
            // hv = (1-ec)*rden = fma(-ec, rden, rden): 1 pk op, shorter chain
            f32x4 hv = __builtin_elementwise_fma(-ec, rden, rden);  // real-unit h

            // f16 pack (RNE via v_cvt_f16_f32) + ONE ds_write_b64 per lane
            f16x4 h16 = { (_Float16)hv[0], (_Float16)hv[1],
                          (_Float16)hv[2], (_Float16)hv[3] };
            *reinterpret_cast<f16x4*>(&hbuf[wb][0][0] + wofs) = h16;

            __syncthreads();   // h(t+1) visible; protects next step's overwrite of rb
        }
        xq = xqn;
    }

    // ---- final FC: out[b] = sum_k h[b][k]*W_fc[k] + b_fc  (h = buf 0 after t=511) ----
    if (tid < 16) {
        int b = tid;
        float s = b_fc[0];
        #pragma unroll 4
        for (int k = 0; k < 64; ++k) {
            s += (float)hbuf[0][b][k] * W_fc[k];
        }
        out[b0 + b] = s;
    }
}

extern "C" void kernel_launch(void* const* d_in, const int* in_sizes, int n_in,
                              void* d_out, int out_size, void* d_ws, size_t ws_size,
                              hipStream_t stream) {
    const float* x    = (const float*)d_in[0];
    const float* W_ih = (const float*)d_in[1];
    const float* W_hh = (const float*)d_in[2];
    const float* b_ih = (const float*)d_in[3];
    const float* b_hh = (const float*)d_in[4];
    const float* W_fc = (const float*)d_in[5];
    const float* b_fc = (const float*)d_in[6];
    float* out = (float*)d_out;
    const int B = in_sizes[0] / T_STEPS;   // 4096
    lstm_persist<<<dim3(B / BT), dim3(256), 0, stream>>>(
        x, W_ih, W_hh, b_ih, b_hh, W_fc, b_fc, out);
}